// Round 1
// baseline (264.469 us; speedup 1.0000x reference)
//
#include <hip/hip_runtime.h>
#include <hip/hip_bf16.h>

#define DIM 512
#define SEQ 2048
#define BATCH 4
#define NHEADS 8
#define DH 64
#define NROWS (BATCH * SEQ)
#define LN_EPS 1e-5f

typedef __hip_bfloat16 bf16;
typedef __attribute__((ext_vector_type(8))) short short8;
typedef __attribute__((ext_vector_type(4))) float f32x4;

#define MFMA_BF16(a, b, c) __builtin_amdgcn_mfma_f32_16x16x32_bf16((a), (b), (c), 0, 0, 0)

// ---------------- LayerNorm + cast to bf16 ----------------
__global__ void ln_kernel(const float* __restrict__ x, const float* __restrict__ gamma,
                          const float* __restrict__ beta, bf16* __restrict__ xn) {
  const int row = blockIdx.x;
  const int t = threadIdx.x;  // 256 threads, 2 elems each
  const float2 v = reinterpret_cast<const float2*>(x + (size_t)row * DIM)[t];
  float s = v.x + v.y;
  float ss = v.x * v.x + v.y * v.y;
#pragma unroll
  for (int off = 32; off > 0; off >>= 1) {
    s += __shfl_down(s, off);
    ss += __shfl_down(ss, off);
  }
  __shared__ float red[8];
  __shared__ float stats[2];
  if ((t & 63) == 0) { red[(t >> 6) * 2] = s; red[(t >> 6) * 2 + 1] = ss; }
  __syncthreads();
  if (t == 0) {
    float S = red[0] + red[2] + red[4] + red[6];
    float SS = red[1] + red[3] + red[5] + red[7];
    float mu = S * (1.0f / DIM);
    float var = SS * (1.0f / DIM) - mu * mu;
    stats[0] = mu;
    stats[1] = rsqrtf(var + LN_EPS);
  }
  __syncthreads();
  const float mu = stats[0], rs = stats[1];
  const float2 gg = reinterpret_cast<const float2*>(gamma)[t];
  const float2 bb = reinterpret_cast<const float2*>(beta)[t];
  __hip_bfloat162 o;
  o.x = __float2bfloat16((v.x - mu) * rs * gg.x + bb.x);
  o.y = __float2bfloat16((v.y - mu) * rs * gg.y + bb.y);
  reinterpret_cast<__hip_bfloat162*>(xn + (size_t)row * DIM)[t] = o;
}

// ---------------- Weight transpose + cast: W[K][N] fp32 -> Wt[N][K] bf16 ----------------
__global__ void wt_kernel(const float* __restrict__ W, bf16* __restrict__ Wt) {
  __shared__ float tile[32][33];
  const int bx = blockIdx.x, by = blockIdx.y;      // bx: n-tile, by: k-tile
  const int tx = threadIdx.x & 31, ty = threadIdx.x >> 5;  // 32 x 8
#pragma unroll
  for (int i = 0; i < 32; i += 8)
    tile[ty + i][tx] = W[(size_t)(by * 32 + ty + i) * DIM + bx * 32 + tx];
  __syncthreads();
#pragma unroll
  for (int i = 0; i < 32; i += 8)
    Wt[(size_t)(bx * 32 + ty + i) * DIM + by * 32 + tx] = __float2bfloat16(tile[tx][ty + i]);
}

// ---------------- QKV GEMM: C[M,N] = A[M,K] @ Wt[N,K]^T, bf16 out ----------------
// z=0 -> q [b][n][512], z=1 -> k [b][n][512], z=2 -> v TRANSPOSED [b][512][seq]
__launch_bounds__(256, 2)
__global__ void gemm_qkv_kernel(const bf16* __restrict__ A, const bf16* __restrict__ WtAll,
                                bf16* __restrict__ qo, bf16* __restrict__ ko,
                                bf16* __restrict__ vto) {
  const int z = blockIdx.z;
  const bf16* __restrict__ Bt = WtAll + (size_t)z * DIM * DIM;
  const int m0 = blockIdx.x * 64, n0 = blockIdx.y * 64;
  __shared__ __align__(16) bf16 sA[64][32];
  __shared__ __align__(16) bf16 sB[64][32];
  const int t = threadIdx.x;
  const int wv = t >> 6, l = t & 63, g = l >> 4, r = l & 15;
  const int wr = (wv >> 1) * 32, wc = (wv & 1) * 32;
  const f32x4 z4 = {0.f, 0.f, 0.f, 0.f};
  f32x4 acc[2][2] = {{z4, z4}, {z4, z4}};
  const int srow = t >> 2, scol = (t & 3) * 8;
  for (int k0 = 0; k0 < DIM; k0 += 32) {
    reinterpret_cast<uint4&>(sA[srow][scol]) =
        *reinterpret_cast<const uint4*>(A + (size_t)(m0 + srow) * DIM + k0 + scol);
    reinterpret_cast<uint4&>(sB[srow][scol]) =
        *reinterpret_cast<const uint4*>(Bt + (size_t)(n0 + srow) * DIM + k0 + scol);
    __syncthreads();
    short8 af[2], bfr[2];
#pragma unroll
    for (int i = 0; i < 2; i++)
      af[i] = *reinterpret_cast<const short8*>(&sA[wr + i * 16 + r][g * 8]);
#pragma unroll
    for (int i = 0; i < 2; i++)
      bfr[i] = *reinterpret_cast<const short8*>(&sB[wc + i * 16 + r][g * 8]);
#pragma unroll
    for (int i = 0; i < 2; i++)
#pragma unroll
      for (int j = 0; j < 2; j++) acc[i][j] = MFMA_BF16(af[i], bfr[j], acc[i][j]);
    __syncthreads();
  }
  const int b = m0 / SEQ;  // 64 | SEQ so the whole block shares b
#pragma unroll
  for (int i = 0; i < 2; i++)
#pragma unroll
    for (int j = 0; j < 2; j++)
#pragma unroll
      for (int reg = 0; reg < 4; reg++) {
        const int m = m0 + wr + i * 16 + g * 4 + reg;   // C row = (lane>>4)*4 + reg
        const int col = n0 + wc + j * 16 + r;           // C col = lane&15
        const bf16 bv = __float2bfloat16(acc[i][j][reg]);
        if (z == 0)      qo[(size_t)m * DIM + col] = bv;
        else if (z == 1) ko[(size_t)m * DIM + col] = bv;
        else             vto[((size_t)b * DIM + col) * SEQ + (m - b * SEQ)] = bv;
      }
}

// ---------------- Flash attention: per block 64 q-rows x one (b,h) ----------------
__launch_bounds__(256, 2)
__global__ void attn_kernel(const bf16* __restrict__ q, const bf16* __restrict__ k,
                            const bf16* __restrict__ vt, bf16* __restrict__ ao) {
  const int it = blockIdx.x, bh = blockIdx.y;
  const int b = bh >> 3, h = bh & 7;
  const int t = threadIdx.x, wv = t >> 6, l = t & 63, g = l >> 4, r = l & 15;
  __shared__ __align__(16) bf16 sK[64][72];       // K-tile [j][d], pad for 8-lane window spread
  __shared__ __align__(16) bf16 sV[64][72];       // V^T-tile [d][j]
  __shared__ __align__(16) bf16 sP[4][16][72];    // per-wave P round-trip buffer
  const float scale = 0.044194173824159216f;      // 512^-0.5 (HIDDEN^-0.5, faithful)
  // Q fragments (A-layout: row = lane&15, k = (lane>>4)*8 + jj)
  const bf16* qbase = q + ((size_t)(b * SEQ + it * 64 + wv * 16 + r)) * DIM + h * DH;
  short8 qf[2];
  qf[0] = *reinterpret_cast<const short8*>(qbase + g * 8);
  qf[1] = *reinterpret_cast<const short8*>(qbase + 32 + g * 8);
  const f32x4 z4 = {0.f, 0.f, 0.f, 0.f};
  f32x4 oacc[4] = {z4, z4, z4, z4};               // O C-layout: rows g*4+reg, col dt*16+r
  float mrow[4] = {-1e30f, -1e30f, -1e30f, -1e30f};
  float lrow[4] = {0.f, 0.f, 0.f, 0.f};
  const int srow = t >> 2, scol = (t & 3) * 8;
  const bf16* kbase = k + ((size_t)(b * SEQ + srow)) * DIM + h * DH + scol;
  const bf16* vbase = vt + ((size_t)(b * DIM + h * DH + srow)) * SEQ + scol;
  for (int jt = 0; jt < SEQ / 64; jt++) {
    const int j0 = jt * 64;
    reinterpret_cast<uint4&>(sK[srow][scol]) =
        *reinterpret_cast<const uint4*>(kbase + (size_t)j0 * DIM);
    reinterpret_cast<uint4&>(sK[srow][scol + 32]) =
        *reinterpret_cast<const uint4*>(kbase + (size_t)j0 * DIM + 32);
    reinterpret_cast<uint4&>(sV[srow][scol]) = *reinterpret_cast<const uint4*>(vbase + j0);
    reinterpret_cast<uint4&>(sV[srow][scol + 32]) =
        *reinterpret_cast<const uint4*>(vbase + j0 + 32);
    __syncthreads();
    // S = Q @ K^T : B-frag lane holds col j = c*16 + (lane&15), k = d = (lane>>4)*8+jj
    f32x4 sc[4];
#pragma unroll
    for (int c = 0; c < 4; c++) {
      const short8 kf0 = *reinterpret_cast<const short8*>(&sK[c * 16 + r][g * 8]);
      const short8 kf1 = *reinterpret_cast<const short8*>(&sK[c * 16 + r][32 + g * 8]);
      f32x4 s = z4;
      s = MFMA_BF16(qf[0], kf0, s);
      s = MFMA_BF16(qf[1], kf1, s);
      sc[c] = s;
    }
    // online softmax over the 64 j's of this tile (row = g*4 + reg, col = lane&15)
    float mnew[4], alpha[4];
#pragma unroll
    for (int reg = 0; reg < 4; reg++) {
      float mx = sc[0][reg] * scale;
#pragma unroll
      for (int c = 1; c < 4; c++) mx = fmaxf(mx, sc[c][reg] * scale);
#pragma unroll
      for (int off = 1; off < 16; off <<= 1) mx = fmaxf(mx, __shfl_xor(mx, off));
      mnew[reg] = fmaxf(mrow[reg], mx);
      alpha[reg] = __expf(mrow[reg] - mnew[reg]);
      mrow[reg] = mnew[reg];
    }
#pragma unroll
    for (int reg = 0; reg < 4; reg++) {
      float rs = 0.f;
#pragma unroll
      for (int c = 0; c < 4; c++) {
        const float p = __expf(sc[c][reg] * scale - mnew[reg]);
        sc[c][reg] = p;
        rs += p;
      }
#pragma unroll
      for (int off = 1; off < 16; off <<= 1) rs += __shfl_xor(rs, off);
      lrow[reg] = lrow[reg] * alpha[reg] + rs;
    }
#pragma unroll
    for (int dt = 0; dt < 4; dt++)
#pragma unroll
      for (int reg = 0; reg < 4; reg++) oacc[dt][reg] *= alpha[reg];
    // P: C-layout -> A-layout via wave-private LDS round trip
#pragma unroll
    for (int c = 0; c < 4; c++)
#pragma unroll
      for (int reg = 0; reg < 4; reg++)
        sP[wv][g * 4 + reg][c * 16 + r] = __float2bfloat16(sc[c][reg]);
    const short8 pf0 = *reinterpret_cast<const short8*>(&sP[wv][r][g * 8]);
    const short8 pf1 = *reinterpret_cast<const short8*>(&sP[wv][r][32 + g * 8]);
    // O += P @ V : B-frag lane holds col d = dt*16+(lane&15), k = j -> read V^T rows
#pragma unroll
    for (int dt = 0; dt < 4; dt++) {
      const short8 vf0 = *reinterpret_cast<const short8*>(&sV[dt * 16 + r][g * 8]);
      const short8 vf1 = *reinterpret_cast<const short8*>(&sV[dt * 16 + r][32 + g * 8]);
      oacc[dt] = MFMA_BF16(pf0, vf0, oacc[dt]);
      oacc[dt] = MFMA_BF16(pf1, vf1, oacc[dt]);
    }
    __syncthreads();
  }
#pragma unroll
  for (int dt = 0; dt < 4; dt++)
#pragma unroll
    for (int reg = 0; reg < 4; reg++) {
      const int i = it * 64 + wv * 16 + g * 4 + reg;
      const int d = dt * 16 + r;
      const float val = oacc[dt][reg] / lrow[reg];
      ao[((size_t)(b * SEQ) + i) * DIM + h * DH + d] = __float2bfloat16(val);
    }
}

// ---------------- Output projection + bias + residual (fp32 out) ----------------
__launch_bounds__(256, 2)
__global__ void gemm_proj_kernel(const bf16* __restrict__ A, const bf16* __restrict__ Bt,
                                 const float* __restrict__ bo, const float* __restrict__ x,
                                 float* __restrict__ out) {
  const int m0 = blockIdx.x * 64, n0 = blockIdx.y * 64;
  __shared__ __align__(16) bf16 sA[64][32];
  __shared__ __align__(16) bf16 sB[64][32];
  const int t = threadIdx.x;
  const int wv = t >> 6, l = t & 63, g = l >> 4, r = l & 15;
  const int wr = (wv >> 1) * 32, wc = (wv & 1) * 32;
  const f32x4 z4 = {0.f, 0.f, 0.f, 0.f};
  f32x4 acc[2][2] = {{z4, z4}, {z4, z4}};
  const int srow = t >> 2, scol = (t & 3) * 8;
  for (int k0 = 0; k0 < DIM; k0 += 32) {
    reinterpret_cast<uint4&>(sA[srow][scol]) =
        *reinterpret_cast<const uint4*>(A + (size_t)(m0 + srow) * DIM + k0 + scol);
    reinterpret_cast<uint4&>(sB[srow][scol]) =
        *reinterpret_cast<const uint4*>(Bt + (size_t)(n0 + srow) * DIM + k0 + scol);
    __syncthreads();
    short8 af[2], bfr[2];
#pragma unroll
    for (int i = 0; i < 2; i++)
      af[i] = *reinterpret_cast<const short8*>(&sA[wr + i * 16 + r][g * 8]);
#pragma unroll
    for (int i = 0; i < 2; i++)
      bfr[i] = *reinterpret_cast<const short8*>(&sB[wc + i * 16 + r][g * 8]);
#pragma unroll
    for (int i = 0; i < 2; i++)
#pragma unroll
      for (int j = 0; j < 2; j++) acc[i][j] = MFMA_BF16(af[i], bfr[j], acc[i][j]);
    __syncthreads();
  }
#pragma unroll
  for (int i = 0; i < 2; i++)
#pragma unroll
    for (int j = 0; j < 2; j++)
#pragma unroll
      for (int reg = 0; reg < 4; reg++) {
        const int m = m0 + wr + i * 16 + g * 4 + reg;
        const int col = n0 + wc + j * 16 + r;
        out[(size_t)m * DIM + col] = acc[i][j][reg] + bo[col] + x[(size_t)m * DIM + col];
      }
}

extern "C" void kernel_launch(void* const* d_in, const int* in_sizes, int n_in,
                              void* d_out, int out_size, void* d_ws, size_t ws_size,
                              hipStream_t stream) {
  (void)in_sizes; (void)n_in; (void)out_size; (void)ws_size;
  const float* x    = (const float*)d_in[0];
  const float* ln_g = (const float*)d_in[1];
  const float* ln_b = (const float*)d_in[2];
  const float* Wq   = (const float*)d_in[3];
  const float* Wk   = (const float*)d_in[4];
  const float* Wv   = (const float*)d_in[5];
  const float* Wo   = (const float*)d_in[6];
  const float* bo   = (const float*)d_in[7];
  float* out = (float*)d_out;
  char* ws = (char*)d_ws;
  // workspace layout (bytes): xn 8MB | Wt(4x) 2MB | q 8MB | k 8MB | v^T 8MB | attn_out 8MB
  bf16* xn  = (bf16*)(ws);
  bf16* wt  = (bf16*)(ws + (8u << 20));
  bf16* qb  = (bf16*)(ws + (10u << 20));
  bf16* kb  = (bf16*)(ws + (18u << 20));
  bf16* vtb = (bf16*)(ws + (26u << 20));
  bf16* aob = (bf16*)(ws + (34u << 20));

  ln_kernel<<<NROWS, 256, 0, stream>>>(x, ln_g, ln_b, xn);
  wt_kernel<<<dim3(16, 16), 256, 0, stream>>>(Wq, wt);
  wt_kernel<<<dim3(16, 16), 256, 0, stream>>>(Wk, wt + DIM * DIM);
  wt_kernel<<<dim3(16, 16), 256, 0, stream>>>(Wv, wt + 2 * DIM * DIM);
  wt_kernel<<<dim3(16, 16), 256, 0, stream>>>(Wo, wt + 3 * DIM * DIM);
  gemm_qkv_kernel<<<dim3(NROWS / 64, DIM / 64, 3), 256, 0, stream>>>(xn, wt, qb, kb, vtb);
  attn_kernel<<<dim3(SEQ / 64, BATCH * NHEADS), 256, 0, stream>>>(qb, kb, vtb, aob);
  gemm_proj_kernel<<<dim3(NROWS / 64, DIM / 64), 256, 0, stream>>>(aob, wt + 3 * DIM * DIM, bo, x, out);
}

// Round 2
// 205.587 us; speedup vs baseline: 1.2864x; 1.2864x over previous
//
#include <hip/hip_runtime.h>
#include <hip/hip_bf16.h>

#define DIM 512
#define SEQ 2048
#define BATCH 4
#define NHEADS 8
#define DH 64
#define NROWS (BATCH * SEQ)
#define LN_EPS 1e-5f

typedef __hip_bfloat16 bf16;
typedef __attribute__((ext_vector_type(8))) short short8;
typedef __attribute__((ext_vector_type(4))) float f32x4;

#define MFMA_BF16(a, b, c) __builtin_amdgcn_mfma_f32_16x16x32_bf16((a), (b), (c), 0, 0, 0)

#if __has_builtin(__builtin_amdgcn_exp2f)
#define EXP2(x) __builtin_amdgcn_exp2f(x)
#else
#define EXP2(x) exp2f(x)
#endif

// scale * log2(e), folded into Wq so attention's softmax is a bare v_exp_f32
#define Q_SCALE_LOG2E 0.06375872f

// ---------------- LayerNorm + cast to bf16 ----------------
__global__ void ln_kernel(const float* __restrict__ x, const float* __restrict__ gamma,
                          const float* __restrict__ beta, bf16* __restrict__ xn) {
  const int row = blockIdx.x;
  const int t = threadIdx.x;  // 256 threads, 2 elems each
  const float2 v = reinterpret_cast<const float2*>(x + (size_t)row * DIM)[t];
  float s = v.x + v.y;
  float ss = v.x * v.x + v.y * v.y;
#pragma unroll
  for (int off = 32; off > 0; off >>= 1) {
    s += __shfl_down(s, off);
    ss += __shfl_down(ss, off);
  }
  __shared__ float red[8];
  __shared__ float stats[2];
  if ((t & 63) == 0) { red[(t >> 6) * 2] = s; red[(t >> 6) * 2 + 1] = ss; }
  __syncthreads();
  if (t == 0) {
    float S = red[0] + red[2] + red[4] + red[6];
    float SS = red[1] + red[3] + red[5] + red[7];
    float mu = S * (1.0f / DIM);
    float var = SS * (1.0f / DIM) - mu * mu;
    stats[0] = mu;
    stats[1] = rsqrtf(var + LN_EPS);
  }
  __syncthreads();
  const float mu = stats[0], rs = stats[1];
  const float2 gg = reinterpret_cast<const float2*>(gamma)[t];
  const float2 bb = reinterpret_cast<const float2*>(beta)[t];
  __hip_bfloat162 o;
  o.x = __float2bfloat16((v.x - mu) * rs * gg.x + bb.x);
  o.y = __float2bfloat16((v.y - mu) * rs * gg.y + bb.y);
  reinterpret_cast<__hip_bfloat162*>(xn + (size_t)row * DIM)[t] = o;
}

// -------- Weight transpose + cast + scale: W[K][N] fp32 -> Wt[N][K] bf16 * scale --------
__global__ void wt_kernel(const float* __restrict__ W, bf16* __restrict__ Wt, float scale) {
  __shared__ float tile[32][33];
  const int bx = blockIdx.x, by = blockIdx.y;      // bx: n-tile, by: k-tile
  const int tx = threadIdx.x & 31, ty = threadIdx.x >> 5;  // 32 x 8
#pragma unroll
  for (int i = 0; i < 32; i += 8)
    tile[ty + i][tx] = W[(size_t)(by * 32 + ty + i) * DIM + bx * 32 + tx];
  __syncthreads();
#pragma unroll
  for (int i = 0; i < 32; i += 8)
    Wt[(size_t)(bx * 32 + ty + i) * DIM + by * 32 + tx] =
        __float2bfloat16(tile[tx][ty + i] * scale);
}

// ---------------- QKV GEMM: C[M,N] = A[M,K] @ Wt[N,K]^T, bf16 out ----------------
// z=0 -> q [b][n][512] (pre-scaled via Wq), z=1 -> k [b][n][512],
// z=2 -> v TRANSPOSED [b][512][seq] via LDS-staged coalesced epilogue
__launch_bounds__(256, 2)
__global__ void gemm_qkv_kernel(const bf16* __restrict__ A, const bf16* __restrict__ WtAll,
                                bf16* __restrict__ qo, bf16* __restrict__ ko,
                                bf16* __restrict__ vto) {
  const int z = blockIdx.z;
  const bf16* __restrict__ Bt = WtAll + (size_t)z * DIM * DIM;
  const int m0 = blockIdx.x * 64, n0 = blockIdx.y * 64;
  __shared__ __align__(16) bf16 sA[64][32];
  __shared__ __align__(16) bf16 sB[64][32];
  __shared__ __align__(16) bf16 sT[64][66];  // v^T staging (z==2 only)
  const int t = threadIdx.x;
  const int wv = t >> 6, l = t & 63, g = l >> 4, r = l & 15;
  const int wr = (wv >> 1) * 32, wc = (wv & 1) * 32;
  const f32x4 z4 = {0.f, 0.f, 0.f, 0.f};
  f32x4 acc[2][2] = {{z4, z4}, {z4, z4}};
  const int srow = t >> 2, scol = (t & 3) * 8;
  for (int k0 = 0; k0 < DIM; k0 += 32) {
    reinterpret_cast<uint4&>(sA[srow][scol]) =
        *reinterpret_cast<const uint4*>(A + (size_t)(m0 + srow) * DIM + k0 + scol);
    reinterpret_cast<uint4&>(sB[srow][scol]) =
        *reinterpret_cast<const uint4*>(Bt + (size_t)(n0 + srow) * DIM + k0 + scol);
    __syncthreads();
    short8 af[2], bfr[2];
#pragma unroll
    for (int i = 0; i < 2; i++)
      af[i] = *reinterpret_cast<const short8*>(&sA[wr + i * 16 + r][g * 8]);
#pragma unroll
    for (int i = 0; i < 2; i++)
      bfr[i] = *reinterpret_cast<const short8*>(&sB[wc + i * 16 + r][g * 8]);
#pragma unroll
    for (int i = 0; i < 2; i++)
#pragma unroll
      for (int j = 0; j < 2; j++) acc[i][j] = MFMA_BF16(af[i], bfr[j], acc[i][j]);
    __syncthreads();
  }
  const int b = m0 / SEQ;  // 64 | SEQ so the whole block shares b
  if (z != 2) {
    bf16* __restrict__ o = (z == 0) ? qo : ko;
#pragma unroll
    for (int i = 0; i < 2; i++)
#pragma unroll
      for (int j = 0; j < 2; j++)
#pragma unroll
        for (int reg = 0; reg < 4; reg++) {
          const int m = m0 + wr + i * 16 + g * 4 + reg;
          const int col = n0 + wc + j * 16 + r;
          o[(size_t)m * DIM + col] = __float2bfloat16(acc[i][j][reg]);
        }
  } else {
    // stage to LDS, then coalesced transposed write (16B along seq)
#pragma unroll
    for (int i = 0; i < 2; i++)
#pragma unroll
      for (int j = 0; j < 2; j++)
#pragma unroll
        for (int reg = 0; reg < 4; reg++)
          sT[wr + i * 16 + g * 4 + reg][wc + j * 16 + r] = __float2bfloat16(acc[i][j][reg]);
    __syncthreads();
    const int col = t >> 2;           // 0..63
    const int mch = (t & 3) * 16;     // 0,16,32,48
    bf16 tmp[16];
#pragma unroll
    for (int k = 0; k < 16; k++) tmp[k] = sT[mch + k][col];
    bf16* dst = vto + ((size_t)b * DIM + n0 + col) * SEQ + (m0 - b * SEQ) + mch;
    reinterpret_cast<uint4*>(dst)[0] = *reinterpret_cast<const uint4*>(&tmp[0]);
    reinterpret_cast<uint4*>(dst)[1] = *reinterpret_cast<const uint4*>(&tmp[8]);
  }
}

// ---------------- Flash attention (no-max softmax, lazy sum) ----------------
// per block: 64 q-rows x one (b,h); Q pre-scaled by scale*log2e -> p = exp2(S)
__launch_bounds__(256, 4)
__global__ void attn_kernel(const bf16* __restrict__ q, const bf16* __restrict__ k,
                            const bf16* __restrict__ vt, bf16* __restrict__ ao) {
  const int it = blockIdx.x, bh = blockIdx.y;
  const int b = bh >> 3, h = bh & 7;
  const int t = threadIdx.x, wv = t >> 6, l = t & 63, g = l >> 4, r = l & 15;
  __shared__ __align__(16) bf16 sK[64][72];     // [j][d]; reads are 2-way (free)
  __shared__ __align__(16) bf16 sV[64][72];     // V^T tile [d][j]
  __shared__ __align__(16) bf16 sP[4][16][68];  // stride 68: write banks g*8 spread, 2-way max
  // Q fragments (A-layout: row = lane&15, k = (lane>>4)*8 + jj)
  const bf16* qbase = q + ((size_t)(b * SEQ + it * 64 + wv * 16 + r)) * DIM + h * DH;
  short8 qf[2];
  qf[0] = *reinterpret_cast<const short8*>(qbase + g * 8);
  qf[1] = *reinterpret_cast<const short8*>(qbase + 32 + g * 8);
  const f32x4 z4 = {0.f, 0.f, 0.f, 0.f};
  f32x4 oacc[4] = {z4, z4, z4, z4};  // O C-layout: rows g*4+reg, col dt*16+r
  float lrow[4] = {0.f, 0.f, 0.f, 0.f};  // per-lane partial softmax denominators
  const int srow = t >> 2, scol = (t & 3) * 8;
  const bf16* kbase = k + ((size_t)(b * SEQ + srow)) * DIM + h * DH + scol;
  const bf16* vbase = vt + ((size_t)(b * DIM + h * DH + srow)) * SEQ + scol;
  // register prefetch pipeline: tile jt in regs while computing jt-1
  uint4 rk0 = *reinterpret_cast<const uint4*>(kbase);
  uint4 rk1 = *reinterpret_cast<const uint4*>(kbase + 32);
  uint4 rv0 = *reinterpret_cast<const uint4*>(vbase);
  uint4 rv1 = *reinterpret_cast<const uint4*>(vbase + 32);
  const int NT = SEQ / 64;
  for (int jt = 0; jt < NT; jt++) {
    reinterpret_cast<uint4&>(sK[srow][scol]) = rk0;
    reinterpret_cast<uint4&>(sK[srow][scol + 32]) = rk1;
    reinterpret_cast<uint4&>(sV[srow][scol]) = rv0;
    reinterpret_cast<uint4&>(sV[srow][scol + 32]) = rv1;
    __syncthreads();
    {  // prefetch next tile (wraps to 0 on last iter — harmless)
      const int j0n = ((jt + 1) & (NT - 1)) * 64;
      rk0 = *reinterpret_cast<const uint4*>(kbase + (size_t)j0n * DIM);
      rk1 = *reinterpret_cast<const uint4*>(kbase + (size_t)j0n * DIM + 32);
      rv0 = *reinterpret_cast<const uint4*>(vbase + j0n);
      rv1 = *reinterpret_cast<const uint4*>(vbase + j0n + 32);
    }
    // S = Q @ K^T (scale+log2e already folded into Q)
    f32x4 sc[4];
#pragma unroll
    for (int c = 0; c < 4; c++) {
      const short8 kf0 = *reinterpret_cast<const short8*>(&sK[c * 16 + r][g * 8]);
      const short8 kf1 = *reinterpret_cast<const short8*>(&sK[c * 16 + r][32 + g * 8]);
      f32x4 s = z4;
      s = MFMA_BF16(qf[0], kf0, s);
      s = MFMA_BF16(qf[1], kf1, s);
      sc[c] = s;
    }
    // p = exp2(S); accumulate per-lane denominator partials (no reductions here)
#pragma unroll
    for (int c = 0; c < 4; c++)
#pragma unroll
      for (int reg = 0; reg < 4; reg++) {
        const float p = EXP2(sc[c][reg]);
        sc[c][reg] = p;
        lrow[reg] += p;
      }
    // P: C-layout -> A-layout via wave-private LDS round trip
#pragma unroll
    for (int c = 0; c < 4; c++)
#pragma unroll
      for (int reg = 0; reg < 4; reg++)
        sP[wv][g * 4 + reg][c * 16 + r] = __float2bfloat16(sc[c][reg]);
    const short8 pf0 = *reinterpret_cast<const short8*>(&sP[wv][r][g * 8]);
    const short8 pf1 = *reinterpret_cast<const short8*>(&sP[wv][r][32 + g * 8]);
    // O += P @ V
#pragma unroll
    for (int dt = 0; dt < 4; dt++) {
      const short8 vf0 = *reinterpret_cast<const short8*>(&sV[dt * 16 + r][g * 8]);
      const short8 vf1 = *reinterpret_cast<const short8*>(&sV[dt * 16 + r][32 + g * 8]);
      oacc[dt] = MFMA_BF16(pf0, vf0, oacc[dt]);
      oacc[dt] = MFMA_BF16(pf1, vf1, oacc[dt]);
    }
    __syncthreads();
  }
  // fold per-lane partials across the 16 lanes of each row group
#pragma unroll
  for (int reg = 0; reg < 4; reg++) {
#pragma unroll
    for (int off = 1; off < 16; off <<= 1) lrow[reg] += __shfl_xor(lrow[reg], off);
    lrow[reg] = 1.0f / lrow[reg];
  }
#pragma unroll
  for (int dt = 0; dt < 4; dt++)
#pragma unroll
    for (int reg = 0; reg < 4; reg++) {
      const int i = it * 64 + wv * 16 + g * 4 + reg;
      const int d = dt * 16 + r;
      ao[((size_t)(b * SEQ) + i) * DIM + h * DH + d] =
          __float2bfloat16(oacc[dt][reg] * lrow[reg]);
    }
}

// ---------------- Output projection + bias + residual (fp32 out) ----------------
__launch_bounds__(256, 2)
__global__ void gemm_proj_kernel(const bf16* __restrict__ A, const bf16* __restrict__ Bt,
                                 const float* __restrict__ bo, const float* __restrict__ x,
                                 float* __restrict__ out) {
  const int m0 = blockIdx.x * 64, n0 = blockIdx.y * 64;
  __shared__ __align__(16) bf16 sA[64][32];
  __shared__ __align__(16) bf16 sB[64][32];
  const int t = threadIdx.x;
  const int wv = t >> 6, l = t & 63, g = l >> 4, r = l & 15;
  const int wr = (wv >> 1) * 32, wc = (wv & 1) * 32;
  const f32x4 z4 = {0.f, 0.f, 0.f, 0.f};
  f32x4 acc[2][2] = {{z4, z4}, {z4, z4}};
  const int srow = t >> 2, scol = (t & 3) * 8;
  for (int k0 = 0; k0 < DIM; k0 += 32) {
    reinterpret_cast<uint4&>(sA[srow][scol]) =
        *reinterpret_cast<const uint4*>(A + (size_t)(m0 + srow) * DIM + k0 + scol);
    reinterpret_cast<uint4&>(sB[srow][scol]) =
        *reinterpret_cast<const uint4*>(Bt + (size_t)(n0 + srow) * DIM + k0 + scol);
    __syncthreads();
    short8 af[2], bfr[2];
#pragma unroll
    for (int i = 0; i < 2; i++)
      af[i] = *reinterpret_cast<const short8*>(&sA[wr + i * 16 + r][g * 8]);
#pragma unroll
    for (int i = 0; i < 2; i++)
      bfr[i] = *reinterpret_cast<const short8*>(&sB[wc + i * 16 + r][g * 8]);
#pragma unroll
    for (int i = 0; i < 2; i++)
#pragma unroll
      for (int j = 0; j < 2; j++) acc[i][j] = MFMA_BF16(af[i], bfr[j], acc[i][j]);
    __syncthreads();
  }
#pragma unroll
  for (int i = 0; i < 2; i++)
#pragma unroll
    for (int j = 0; j < 2; j++)
#pragma unroll
      for (int reg = 0; reg < 4; reg++) {
        const int m = m0 + wr + i * 16 + g * 4 + reg;
        const int col = n0 + wc + j * 16 + r;
        out[(size_t)m * DIM + col] = acc[i][j][reg] + bo[col] + x[(size_t)m * DIM + col];
      }
}

extern "C" void kernel_launch(void* const* d_in, const int* in_sizes, int n_in,
                              void* d_out, int out_size, void* d_ws, size_t ws_size,
                              hipStream_t stream) {
  (void)in_sizes; (void)n_in; (void)out_size; (void)ws_size;
  const float* x    = (const float*)d_in[0];
  const float* ln_g = (const float*)d_in[1];
  const float* ln_b = (const float*)d_in[2];
  const float* Wq   = (const float*)d_in[3];
  const float* Wk   = (const float*)d_in[4];
  const float* Wv   = (const float*)d_in[5];
  const float* Wo   = (const float*)d_in[6];
  const float* bo   = (const float*)d_in[7];
  float* out = (float*)d_out;
  char* ws = (char*)d_ws;
  // workspace layout (bytes): xn 8MB | Wt(4x) 2MB | q 8MB | k 8MB | v^T 8MB | attn_out 8MB
  bf16* xn  = (bf16*)(ws);
  bf16* wt  = (bf16*)(ws + (8u << 20));
  bf16* qb  = (bf16*)(ws + (10u << 20));
  bf16* kb  = (bf16*)(ws + (18u << 20));
  bf16* vtb = (bf16*)(ws + (26u << 20));
  bf16* aob = (bf16*)(ws + (34u << 20));

  ln_kernel<<<NROWS, 256, 0, stream>>>(x, ln_g, ln_b, xn);
  wt_kernel<<<dim3(16, 16), 256, 0, stream>>>(Wq, wt, Q_SCALE_LOG2E);
  wt_kernel<<<dim3(16, 16), 256, 0, stream>>>(Wk, wt + DIM * DIM, 1.0f);
  wt_kernel<<<dim3(16, 16), 256, 0, stream>>>(Wv, wt + 2 * DIM * DIM, 1.0f);
  wt_kernel<<<dim3(16, 16), 256, 0, stream>>>(Wo, wt + 3 * DIM * DIM, 1.0f);
  gemm_qkv_kernel<<<dim3(NROWS / 64, DIM / 64, 3), 256, 0, stream>>>(xn, wt, qb, kb, vtb);
  attn_kernel<<<dim3(SEQ / 64, BATCH * NHEADS), 256, 0, stream>>>(qb, kb, vtb, aob);
  gemm_proj_kernel<<<dim3(NROWS / 64, DIM / 64), 256, 0, stream>>>(aob, wt + 3 * DIM * DIM, bo, x, out);
}